// Round 7
// baseline (1977.627 us; speedup 1.0000x reference)
//
#include <hip/hip_runtime.h>

typedef __bf16 bf16;
typedef bf16 bf16x8 __attribute__((ext_vector_type(8)));
typedef float f32x4 __attribute__((ext_vector_type(4)));
typedef unsigned long u64x2 __attribute__((ext_vector_type(2)));

#define AS1 __attribute__((address_space(1)))
#define AS3 __attribute__((address_space(3)))

#define B_ 2048
#define T_ 80
#define E_ 100
#define H_ 512
#define TC_ 16              // time-chunk
#define NC_ (T_ / TC_)      // 5 chunks
#define ROWS_ 16            // batch rows per rnn block
#define NTASK_ 20           // 4 layers x 5 chunks

// SEQ is TIME-MAJOR: seq[(t*B_ + b)*H_ + h]
// U fp8 CONTIGUOUS-FRAGMENT layout: colblock c (cols c*16..+15), kk-pair p ->
// 1024B block at (c*8+p)*1024; byte[lane*16 + half*8 + j] =
//   U[k=(2p+half)*32 + (lane>>4)*8 + j][n=c*16 + (lane&15)] * 2^6.

__device__ __forceinline__ float fast_tanh(float x) {
  float e = exp2f(x * 2.8853900817779268f);  // e^{2x}
  return 1.f - 2.f * __builtin_amdgcn_rcpf(e + 1.f);
}

__device__ __forceinline__ unsigned char to_fp8(float v) {
  return (unsigned char)(__builtin_amdgcn_cvt_pk_fp8_f32(v, v, 0, false) & 0xff);
}

__device__ __forceinline__ long pack_fp8x8(const float* f) {
  int w0 = __builtin_amdgcn_cvt_pk_fp8_f32(f[0], f[1], 0, false);
  w0 = __builtin_amdgcn_cvt_pk_fp8_f32(f[2], f[3], w0, true);
  int w1 = __builtin_amdgcn_cvt_pk_fp8_f32(f[4], f[5], 0, false);
  w1 = __builtin_amdgcn_cvt_pk_fp8_f32(f[6], f[7], w1, true);
  return (long)(((unsigned long)(unsigned)w1 << 32) | (unsigned)w0);
}

// dst[n*Kp + k] = k<K ? src[k*N + n] : 0
__global__ void convert_weight(const float* __restrict__ src, bf16* __restrict__ dst,
                               int K, int Kp, int N) {
  int idx = blockIdx.x * 256 + threadIdx.x;
  if (idx >= N * Kp) return;
  int n = idx / Kp, k = idx - n * Kp;
  float v = (k < K) ? src[(long)k * N + n] : 0.f;
  dst[idx] = (bf16)v;
}

// U[512x512] fp32 -> fp8 e4m3 * 2^6, contiguous-fragment layout.
__global__ void convert_u_fp8(const float* __restrict__ src, unsigned char* __restrict__ dst) {
  int idx = blockIdx.x * 256 + threadIdx.x;
  int half = idx & 1, lane = (idx >> 1) & 63, p = (idx >> 7) & 7, c = idx >> 10;
  int k0 = (2 * p + half) * 32 + (lane >> 4) * 8;
  int n = c * 16 + (lane & 15);
  float f[8];
#pragma unroll
  for (int j = 0; j < 8; j++) f[j] = src[(long)(k0 + j) * H_ + n] * 64.f;
  *(long*)(dst + (long)(c * 8 + p) * 1024 + lane * 16 + half * 8) = pack_fp8x8(f);
}

// ---- GEMM tile device functions (256-thread sub-group, 16KB+16KB LDS slice) ----

// C[mtile*128..+127, ntile*128..+127] = A @ Bt^T, K=512
__device__ __forceinline__ void gemm_tile(
    const bf16* __restrict__ A, const bf16* __restrict__ Bt, bf16* __restrict__ C,
    int mtile, int ntile, int stid, char* base) {
  bf16* As = (bf16*)base;
  bf16* Bs = (bf16*)(base + 8192);
  const int K = 512;
  const int wave = stid >> 6, lane = stid & 63;
  const int l = lane & 15, q = lane >> 4;
  const long m0 = (long)mtile * 128;
  const int n0 = ntile * 128;
  const int wm = (wave >> 1) * 64, wn = (wave & 1) * 64;

  f32x4 acc[4][4] = {};

  const int e0 = stid, e1 = 256 + stid;
  const int r0 = e0 >> 2, c0 = e0 & 3;
  const int r1 = e1 >> 2, c1 = e1 & 3;
  const int s0 = c0 ^ (r0 & 3) ^ ((r0 >> 2) & 3);
  const int s1 = c1 ^ (r1 & 3) ^ ((r1 >> 2) & 3);
  const int swr = q ^ (l & 3) ^ ((l >> 2) & 3);

  const bf16* A0 = A + (m0 + r0) * K + s0 * 8;
  const bf16* A1 = A + (m0 + r1) * K + s1 * 8;
  const bf16* B0 = Bt + (long)(n0 + r0) * K + s0 * 8;
  const bf16* B1 = Bt + (long)(n0 + r1) * K + s1 * 8;
  bf16* AsW0 = As + (wave * 64) * 8;
  bf16* AsW1 = As + (256 + wave * 64) * 8;
  bf16* BsW0 = Bs + (wave * 64) * 8;
  bf16* BsW1 = Bs + (256 + wave * 64) * 8;

  for (int k0 = 0; k0 < K; k0 += 32) {
    __builtin_amdgcn_global_load_lds((const AS1 void*)(A0 + k0), (AS3 void*)AsW0, 16, 0, 0);
    __builtin_amdgcn_global_load_lds((const AS1 void*)(A1 + k0), (AS3 void*)AsW1, 16, 0, 0);
    __builtin_amdgcn_global_load_lds((const AS1 void*)(B0 + k0), (AS3 void*)BsW0, 16, 0, 0);
    __builtin_amdgcn_global_load_lds((const AS1 void*)(B1 + k0), (AS3 void*)BsW1, 16, 0, 0);
    __syncthreads();
    bf16x8 af[4], bfm[4];
#pragma unroll
    for (int i = 0; i < 4; i++) {
      af[i]  = *(const bf16x8*)(As + (wm + i * 16 + l) * 32 + swr * 8);
      bfm[i] = *(const bf16x8*)(Bs + (wn + i * 16 + l) * 32 + swr * 8);
    }
#pragma unroll
    for (int i = 0; i < 4; i++)
#pragma unroll
      for (int j = 0; j < 4; j++)
        acc[i][j] = __builtin_amdgcn_mfma_f32_16x16x32_bf16(af[i], bfm[j], acc[i][j], 0, 0, 0);
    __syncthreads();
  }
#pragma unroll
  for (int i = 0; i < 4; i++)
#pragma unroll
    for (int j = 0; j < 4; j++)
#pragma unroll
      for (int r = 0; r < 4; r++)
        C[(m0 + wm + i * 16 + q * 4 + r) * (long)H_ + n0 + wn + j * 16 + l] =
            (bf16)acc[i][j][r];
}

// layer-1 tile with fused embedding gather; xidx -> (trow, b0); K=128 (padded E)
__device__ __forceinline__ void gemm_tile_embed(
    const int* __restrict__ tokens, const float* __restrict__ emb,
    const bf16* __restrict__ Bt, bf16* __restrict__ xwc, int t0,
    int xidx, int ntile, int stid, char* base) {
  bf16* As = (bf16*)base;
  bf16* Bs = (bf16*)(base + 8192);
  int* stok = (int*)(base + 16384);
  const int K = 128;
  const int wave = stid >> 6, lane = stid & 63;
  const int l = lane & 15, q = lane >> 4;
  const int trow = xidx >> 4;
  const int b0 = (xidx & 15) * 128;
  const int t = t0 + trow;
  const int n0 = ntile * 128;
  const int wm = (wave >> 1) * 64, wn = (wave & 1) * 64;

  if (stid < 128) stok[stid] = tokens[(b0 + stid) * T_ + t];
  __syncthreads();

  f32x4 acc[4][4] = {};

  const int e0 = stid, e1 = 256 + stid;
  const int r0 = e0 >> 2, c0 = e0 & 3;
  const int r1 = e1 >> 2, c1 = e1 & 3;
  const int s0 = c0 ^ (r0 & 3) ^ ((r0 >> 2) & 3);
  const int s1 = c1 ^ (r1 & 3) ^ ((r1 >> 2) & 3);
  const int swr = q ^ (l & 3) ^ ((l >> 2) & 3);

  const bf16* B0 = Bt + (long)(n0 + r0) * K + s0 * 8;
  const bf16* B1 = Bt + (long)(n0 + r1) * K + s1 * 8;
  bf16* BsW0 = Bs + (wave * 64) * 8;
  bf16* BsW1 = Bs + (256 + wave * 64) * 8;

  const int ar = stid >> 1, hh = stid & 1;
  const int asw = (ar & 3) ^ ((ar >> 2) & 3);
  const float* er = emb + (long)stok[ar] * E_;

  for (int k0 = 0; k0 < K; k0 += 32) {
    __builtin_amdgcn_global_load_lds((const AS1 void*)(B0 + k0), (AS3 void*)BsW0, 16, 0, 0);
    __builtin_amdgcn_global_load_lds((const AS1 void*)(B1 + k0), (AS3 void*)BsW1, 16, 0, 0);
    bf16x8 v[2];
#pragma unroll
    for (int cch = 0; cch < 2; cch++) {
      int kb = k0 + hh * 16 + cch * 8;
#pragma unroll
      for (int j = 0; j < 8; j++) {
        int k = kb + j;
        v[cch][j] = (bf16)((k < E_) ? er[k] : 0.f);
      }
    }
    *(bf16x8*)(As + ar * 32 + ((2 * hh + 0) ^ asw) * 8) = v[0];
    *(bf16x8*)(As + ar * 32 + ((2 * hh + 1) ^ asw) * 8) = v[1];
    __syncthreads();
    bf16x8 af[4], bfm[4];
#pragma unroll
    for (int i = 0; i < 4; i++) {
      af[i]  = *(const bf16x8*)(As + (wm + i * 16 + l) * 32 + swr * 8);
      bfm[i] = *(const bf16x8*)(Bs + (wn + i * 16 + l) * 32 + swr * 8);
    }
#pragma unroll
    for (int i = 0; i < 4; i++)
#pragma unroll
      for (int j = 0; j < 4; j++)
        acc[i][j] = __builtin_amdgcn_mfma_f32_16x16x32_bf16(af[i], bfm[j], acc[i][j], 0, 0, 0);
    __syncthreads();
  }
  bf16* C = xwc + ((long)trow * B_ + b0) * H_;
#pragma unroll
  for (int i = 0; i < 4; i++)
#pragma unroll
    for (int j = 0; j < 4; j++)
#pragma unroll
      for (int r = 0; r < 4; r++)
        C[(long)(wm + i * 16 + q * 4 + r) * H_ + n0 + wn + j * 16 + l] =
            (bf16)acc[i][j][r];
}

// ---- Fused pipeline step: blocks 0..127 rnn(task t-1), blocks 128..255 gemm(task t) ----
// gemm_wide=1: all 256 blocks do gemm (1 tile per sub-group), rnn off.
__global__ __launch_bounds__(1024) void fused_step(
    const bf16* __restrict__ xwc_r, const unsigned char* __restrict__ U8,
    const float* __restrict__ bias, bf16* __restrict__ seq, int t0_r, int first,
    int rnn_on,
    const bf16* __restrict__ A, const bf16* __restrict__ Bt,
    bf16* __restrict__ xwc_g, int gemm_kind, int gemm_wide,
    const int* __restrict__ tokens, const float* __restrict__ emb, int t0_g) {
  __shared__ __align__(16) char smem[116480];
  const int tid = threadIdx.x;

  if (blockIdx.x < 128 && !gemm_wide) {
    if (!rnn_on) return;
    // ---------------- rnn path ----------------
    char* hls8 = smem;                               // 2 x 16 x 520 B fp8 h
    bf16* xws = (bf16*)(smem + 16640);               // 4-buf xw staging
    bf16* hstg = (bf16*)(smem + 16640 + 66560);      // 2-buf bf16 h staging
    const int wave = tid >> 6, lane = tid & 63;
    const int l = lane & 15, q = lane >> 4;
    const int b0 = blockIdx.x * ROWS_;

    {
      long pk = 0;
      if (!first) {
        const bf16* hsrc = seq + ((long)(t0_r - 1) * B_ + b0 + wave) * H_;
        bf16x8 v = *(const bf16x8*)(hsrc + lane * 8);
        float f[8];
#pragma unroll
        for (int j = 0; j < 8; j++) f[j] = (float)v[j] * 16.f;
        pk = pack_fp8x8(f);
      }
      *(long*)(hls8 + wave * 520 + lane * 8) = pk;
    }

    float bb[2];
#pragma unroll
    for (int nt = 0; nt < 2; nt++) bb[nt] = bias[wave * 32 + nt * 16 + l];

    auto prefetch = [&](int tl) {
      int buf = tl & 3;
      __builtin_amdgcn_global_load_lds(
          (const AS1 void*)(xwc_r + ((long)tl * B_ + b0 + wave) * H_ + lane * 8),
          (AS3 void*)(xws + (buf * ROWS_ + wave) * 520), 16, 0, 0);
    };

    prefetch(0);
    prefetch(1);
    __syncthreads();

    const unsigned char* Ub = U8 + (long)(wave * 2) * 8192 + lane * 16;

    for (int tl = 0; tl < TC_; tl++) {
      if (tl + 2 < TC_) prefetch(tl + 2);

      const char* hb8 = hls8 + ((tl & 1) * ROWS_ + l) * 520 + q * 8;
      f32x4 acc[2] = {};
      u64x2 bfr[4][2];
#pragma unroll
      for (int d = 0; d < 4; d++)
#pragma unroll
        for (int nt = 0; nt < 2; nt++)
          bfr[d][nt] = *(const u64x2*)(Ub + nt * 8192 + d * 1024);
#pragma unroll
      for (int kk2 = 0; kk2 < 8; kk2++) {
        const int cur = kk2 & 3;
        long a0 = *(const long*)(hb8 + kk2 * 64);
        long a1 = *(const long*)(hb8 + kk2 * 64 + 32);
#pragma unroll
        for (int nt = 0; nt < 2; nt++)
          acc[nt] = __builtin_amdgcn_mfma_f32_16x16x32_fp8_fp8(a0, (long)bfr[cur][nt].x,
                                                               acc[nt], 0, 0, 0);
#pragma unroll
        for (int nt = 0; nt < 2; nt++)
          acc[nt] = __builtin_amdgcn_mfma_f32_16x16x32_fp8_fp8(a1, (long)bfr[cur][nt].y,
                                                               acc[nt], 0, 0, 0);
        if (kk2 < 4) {
#pragma unroll
          for (int nt = 0; nt < 2; nt++)
            bfr[cur][nt] = *(const u64x2*)(Ub + nt * 8192 + (kk2 + 4) * 1024);
        }
      }
      const bf16* xr = xws + ((tl & 3) * ROWS_ + q * 4) * 520 + wave * 32 + l;
      float hv[2][4];
#pragma unroll
      for (int nt = 0; nt < 2; nt++)
#pragma unroll
        for (int r = 0; r < 4; r++)
          hv[nt][r] = fast_tanh((float)xr[r * 520 + nt * 16] + bb[nt] +
                                acc[nt][r] * 0.0009765625f);

#pragma unroll
      for (int nt = 0; nt < 2; nt++) {
        int n = wave * 32 + nt * 16 + l;
#pragma unroll
        for (int r = 0; r < 4; r++) {
          int m = q * 4 + r;
          hls8[(((tl + 1) & 1) * ROWS_ + m) * 520 + n] = (char)to_fp8(hv[nt][r] * 16.f);
          hstg[((tl & 1) * ROWS_ + m) * 520 + n] = (bf16)hv[nt][r];
        }
      }

      if (tl > 0) {
        bf16* sp = seq + ((long)(t0_r + tl - 1) * B_ + b0 + wave) * H_;
        *(bf16x8*)(sp + lane * 8) =
            *(const bf16x8*)(hstg + (((tl - 1) & 1) * ROWS_ + wave) * 520 + lane * 8);
      }

      __syncthreads();
    }
    {
      bf16* sp = seq + ((long)(t0_r + TC_ - 1) * B_ + b0 + wave) * H_;
      *(bf16x8*)(sp + lane * 8) =
          *(const bf16x8*)(hstg + (((TC_ - 1) & 1) * ROWS_ + wave) * 520 + lane * 8);
    }
    return;
  }

  // ---------------- gemm path ----------------
  if (!gemm_kind) return;
  const int sub = tid >> 8, stid = tid & 255;
  char* base = smem + sub * 17408;
  const int gb = gemm_wide ? blockIdx.x : blockIdx.x - 128;
  const int reps = gemm_wide ? 1 : 2;
  const int sb = gb * 4 + sub;
  for (int rep = 0; rep < reps; rep++) {
    int tau = sb + rep * 512;
    int x = tau & 255, y = tau >> 8;
    if (gemm_kind == 1)
      gemm_tile_embed(tokens, emb, Bt, xwc_g, t0_g, x, y, stid, base);
    else
      gemm_tile(A, Bt, xwc_g, x, y, stid, base);
  }
}

// out[b] = sigmoid(dot(seq[(T-1)*B + b, :], Wo) + bo)
__global__ __launch_bounds__(256) void head_kernel(
    const bf16* __restrict__ seq, const float* __restrict__ Wo,
    const float* __restrict__ bo, float* __restrict__ out) {
  int wave = threadIdx.x >> 6, lane = threadIdx.x & 63;
  int row = blockIdx.x * 4 + wave;
  const bf16* p = seq + ((long)(T_ - 1) * B_ + row) * H_ + lane * 8;
  bf16x8 v = *(const bf16x8*)p;
  float s = 0.f;
#pragma unroll
  for (int i = 0; i < 8; i++) s += (float)v[i] * Wo[lane * 8 + i];
#pragma unroll
  for (int off = 32; off; off >>= 1) s += __shfl_down(s, off, 64);
  if (lane == 0) {
    float x = s + bo[0];
    out[row] = 1.f / (1.f + exp2f(-x * 1.44269504088896f));
  }
}

extern "C" void kernel_launch(void* const* d_in, const int* in_sizes, int n_in,
                              void* d_out, int out_size, void* d_ws, size_t ws_size,
                              hipStream_t stream) {
  (void)in_sizes; (void)n_in; (void)out_size;
  const int*   tokens = (const int*)d_in[0];
  const float* emb = (const float*)d_in[1];
  const float* W1 = (const float*)d_in[2];
  const float* U1 = (const float*)d_in[3];
  const float* b1 = (const float*)d_in[4];
  const float* W2 = (const float*)d_in[5];
  const float* U2 = (const float*)d_in[6];
  const float* b2 = (const float*)d_in[7];
  const float* W3 = (const float*)d_in[8];
  const float* U3 = (const float*)d_in[9];
  const float* b3 = (const float*)d_in[10];
  const float* W4 = (const float*)d_in[11];
  const float* U4 = (const float*)d_in[12];
  const float* b4 = (const float*)d_in[13];
  const float* Wo = (const float*)d_in[14];
  const float* bo = (const float*)d_in[15];
  float* out = (float*)d_out;

  char* w = (char*)d_ws;
  const size_t SEQ_BYTES = (size_t)T_ * B_ * H_ * 2;   // 160 MB
  const size_t XWC_BYTES = (size_t)TC_ * B_ * H_ * 2;  // 32 MB
  const size_t WEIGHTS = 512 * 128 * 2 + 3 * 512 * 512 * 2 + 4 * 512 * 512;
  const bool dbl = ws_size >= SEQ_BYTES + 2 * XWC_BYTES + WEIGHTS;

  bf16* SEQ = (bf16*)w;
  bf16* XWC0 = (bf16*)(w + SEQ_BYTES);
  bf16* XWC1 = dbl ? (bf16*)(w + SEQ_BYTES + XWC_BYTES) : XWC0;
  char* wb = w + SEQ_BYTES + (dbl ? 2 : 1) * XWC_BYTES;
  bf16* W1t = (bf16*)wb;
  bf16* W2t = W1t + 512 * 128;
  bf16* W3t = W2t + 512 * 512;
  bf16* W4t = W3t + 512 * 512;
  unsigned char* U1p = (unsigned char*)(W4t + 512 * 512);
  unsigned char* U2p = U1p + 512 * 512;
  unsigned char* U3p = U2p + 512 * 512;
  unsigned char* U4p = U3p + 512 * 512;

  convert_weight<<<(512 * 128) / 256, 256, 0, stream>>>(W1, W1t, 100, 128, 512);
  convert_weight<<<(512 * 512) / 256, 256, 0, stream>>>(W2, W2t, 512, 512, 512);
  convert_weight<<<(512 * 512) / 256, 256, 0, stream>>>(W3, W3t, 512, 512, 512);
  convert_weight<<<(512 * 512) / 256, 256, 0, stream>>>(W4, W4t, 512, 512, 512);
  convert_u_fp8<<<128, 256, 0, stream>>>(U1, U1p);
  convert_u_fp8<<<128, 256, 0, stream>>>(U2, U2p);
  convert_u_fp8<<<128, 256, 0, stream>>>(U3, U3p);
  convert_u_fp8<<<128, 256, 0, stream>>>(U4, U4p);

  const bf16* Wt[4] = {W1t, W2t, W3t, W4t};
  const unsigned char* Up[4] = {U1p, U2p, U3p, U4p};
  const float* bs[4] = {b1, b2, b3, b4};
  bf16* XWCb[2] = {XWC0, XWC1};

  if (dbl) {
    // software pipeline: launch t = rnn(task t-1) || gemm(task t)
    for (int t = 0; t <= NTASK_; t++) {
      int rt = t - 1;
      int rl = rt < 0 ? 0 : rt / NC_, rc = rt < 0 ? 0 : rt % NC_;
      int gl = t >= NTASK_ ? 0 : t / NC_, gc = t >= NTASK_ ? 0 : t % NC_;
      int gkind = t >= NTASK_ ? 0 : (gl == 0 ? 1 : 2);
      int wide = (t == 0) ? 1 : 0;
      fused_step<<<256, 1024, 0, stream>>>(
          XWCb[rt & 1], Up[rl], bs[rl], SEQ, rc * TC_, rc == 0 ? 1 : 0,
          rt >= 0 ? 1 : 0,
          SEQ + (size_t)gc * TC_ * B_ * H_, Wt[gl], XWCb[t & 1], gkind, wide,
          tokens, emb, gc * TC_);
    }
  } else {
    // serial fallback: one XWC buffer
    for (int t = 0; t < NTASK_; t++) {
      int l = t / NC_, c = t % NC_;
      int gkind = (l == 0 ? 1 : 2);
      fused_step<<<256, 1024, 0, stream>>>(
          XWC0, Up[l], bs[l], SEQ, c * TC_, 0, 0,
          SEQ + (size_t)c * TC_ * B_ * H_, Wt[l], XWC0, gkind, 1,
          tokens, emb, c * TC_);
      fused_step<<<256, 1024, 0, stream>>>(
          XWC0, Up[l], bs[l], SEQ, c * TC_, c == 0 ? 1 : 0, 1,
          SEQ, Wt[l], XWC0, 0, 0, tokens, emb, 0);
    }
  }

  head_kernel<<<B_ / 4, 256, 0, stream>>>(SEQ, Wo, bo, out);
}

// Round 8
// 1339.131 us; speedup vs baseline: 1.4768x; 1.4768x over previous
//
#include <hip/hip_runtime.h>

typedef __bf16 bf16;
typedef bf16 bf16x8 __attribute__((ext_vector_type(8)));
typedef float f32x4 __attribute__((ext_vector_type(4)));
typedef unsigned long u64x2 __attribute__((ext_vector_type(2)));

#define AS1 __attribute__((address_space(1)))
#define AS3 __attribute__((address_space(3)))

#define B_ 2048
#define T_ 80
#define E_ 100
#define H_ 512
#define TC_ 16              // time-chunk
#define NC_ (T_ / TC_)      // 5 chunks
#define ROWS_ 16            // batch rows per rnn block
#define NTASK_ 20           // 4 layers x 5 chunks

// SEQ is TIME-MAJOR: seq[(t*B_ + b)*H_ + h]
// U fp8 CONTIGUOUS-FRAGMENT layout: colblock c (cols c*16..+15), kk-pair p ->
// 1024B block at (c*8+p)*1024; byte[lane*16 + half*8 + j] =
//   U[k=(2p+half)*32 + (lane>>4)*8 + j][n=c*16 + (lane&15)] * 2^6.

__device__ __forceinline__ float fast_tanh(float x) {
  float e = exp2f(x * 2.8853900817779268f);  // e^{2x}
  return 1.f - 2.f * __builtin_amdgcn_rcpf(e + 1.f);
}

__device__ __forceinline__ unsigned char to_fp8(float v) {
  return (unsigned char)(__builtin_amdgcn_cvt_pk_fp8_f32(v, v, 0, false) & 0xff);
}

__device__ __forceinline__ long pack_fp8x8(const float* f) {
  int w0 = __builtin_amdgcn_cvt_pk_fp8_f32(f[0], f[1], 0, false);
  w0 = __builtin_amdgcn_cvt_pk_fp8_f32(f[2], f[3], w0, true);
  int w1 = __builtin_amdgcn_cvt_pk_fp8_f32(f[4], f[5], 0, false);
  w1 = __builtin_amdgcn_cvt_pk_fp8_f32(f[6], f[7], w1, true);
  return (long)(((unsigned long)(unsigned)w1 << 32) | (unsigned)w0);
}

// dst[n*Kp + k] = k<K ? src[k*N + n] : 0
__global__ void convert_weight(const float* __restrict__ src, bf16* __restrict__ dst,
                               int K, int Kp, int N) {
  int idx = blockIdx.x * 256 + threadIdx.x;
  if (idx >= N * Kp) return;
  int n = idx / Kp, k = idx - n * Kp;
  float v = (k < K) ? src[(long)k * N + n] : 0.f;
  dst[idx] = (bf16)v;
}

// U[512x512] fp32 -> fp8 e4m3 * 2^6, contiguous-fragment layout.
__global__ void convert_u_fp8(const float* __restrict__ src, unsigned char* __restrict__ dst) {
  int idx = blockIdx.x * 256 + threadIdx.x;
  int half = idx & 1, lane = (idx >> 1) & 63, p = (idx >> 7) & 7, c = idx >> 10;
  int k0 = (2 * p + half) * 32 + (lane >> 4) * 8;
  int n = c * 16 + (lane & 15);
  float f[8];
#pragma unroll
  for (int j = 0; j < 8; j++) f[j] = src[(long)(k0 + j) * H_ + n] * 64.f;
  *(long*)(dst + (long)(c * 8 + p) * 1024 + lane * 16 + half * 8) = pack_fp8x8(f);
}

// ---- GEMM tile device functions (256-thread sub-group, 17408B LDS slice) ----

// C[mtile*128..+127, ntile*128..+127] = A @ Bt^T, K=512
__device__ __forceinline__ void gemm_tile(
    const bf16* __restrict__ A, const bf16* __restrict__ Bt, bf16* __restrict__ C,
    int mtile, int ntile, int stid, char* base) {
  bf16* As = (bf16*)base;
  bf16* Bs = (bf16*)(base + 8192);
  const int K = 512;
  const int wave = stid >> 6, lane = stid & 63;
  const int l = lane & 15, q = lane >> 4;
  const long m0 = (long)mtile * 128;
  const int n0 = ntile * 128;
  const int wm = (wave >> 1) * 64, wn = (wave & 1) * 64;

  f32x4 acc[4][4] = {};

  const int e0 = stid, e1 = 256 + stid;
  const int r0 = e0 >> 2, c0 = e0 & 3;
  const int r1 = e1 >> 2, c1 = e1 & 3;
  const int s0 = c0 ^ (r0 & 3) ^ ((r0 >> 2) & 3);
  const int s1 = c1 ^ (r1 & 3) ^ ((r1 >> 2) & 3);
  const int swr = q ^ (l & 3) ^ ((l >> 2) & 3);

  const bf16* A0 = A + (m0 + r0) * K + s0 * 8;
  const bf16* A1 = A + (m0 + r1) * K + s1 * 8;
  const bf16* B0 = Bt + (long)(n0 + r0) * K + s0 * 8;
  const bf16* B1 = Bt + (long)(n0 + r1) * K + s1 * 8;
  bf16* AsW0 = As + (wave * 64) * 8;
  bf16* AsW1 = As + (256 + wave * 64) * 8;
  bf16* BsW0 = Bs + (wave * 64) * 8;
  bf16* BsW1 = Bs + (256 + wave * 64) * 8;

  for (int k0 = 0; k0 < K; k0 += 32) {
    __builtin_amdgcn_global_load_lds((const AS1 void*)(A0 + k0), (AS3 void*)AsW0, 16, 0, 0);
    __builtin_amdgcn_global_load_lds((const AS1 void*)(A1 + k0), (AS3 void*)AsW1, 16, 0, 0);
    __builtin_amdgcn_global_load_lds((const AS1 void*)(B0 + k0), (AS3 void*)BsW0, 16, 0, 0);
    __builtin_amdgcn_global_load_lds((const AS1 void*)(B1 + k0), (AS3 void*)BsW1, 16, 0, 0);
    __syncthreads();
    bf16x8 af[4], bfm[4];
#pragma unroll
    for (int i = 0; i < 4; i++) {
      af[i]  = *(const bf16x8*)(As + (wm + i * 16 + l) * 32 + swr * 8);
      bfm[i] = *(const bf16x8*)(Bs + (wn + i * 16 + l) * 32 + swr * 8);
    }
#pragma unroll
    for (int i = 0; i < 4; i++)
#pragma unroll
      for (int j = 0; j < 4; j++)
        acc[i][j] = __builtin_amdgcn_mfma_f32_16x16x32_bf16(af[i], bfm[j], acc[i][j], 0, 0, 0);
    __syncthreads();
  }
#pragma unroll
  for (int i = 0; i < 4; i++)
#pragma unroll
    for (int j = 0; j < 4; j++)
#pragma unroll
      for (int r = 0; r < 4; r++)
        C[(m0 + wm + i * 16 + q * 4 + r) * (long)H_ + n0 + wn + j * 16 + l] =
            (bf16)acc[i][j][r];
}

// layer-1 tile with fused embedding gather; xidx -> (trow, b0); K=128 (padded E)
__device__ __forceinline__ void gemm_tile_embed(
    const int* __restrict__ tokens, const float* __restrict__ emb,
    const bf16* __restrict__ Bt, bf16* __restrict__ xwc, int t0,
    int xidx, int ntile, int stid, char* base) {
  bf16* As = (bf16*)base;
  bf16* Bs = (bf16*)(base + 8192);
  int* stok = (int*)(base + 16384);
  const int K = 128;
  const int wave = stid >> 6, lane = stid & 63;
  const int l = lane & 15, q = lane >> 4;
  const int trow = xidx >> 4;
  const int b0 = (xidx & 15) * 128;
  const int t = t0 + trow;
  const int n0 = ntile * 128;
  const int wm = (wave >> 1) * 64, wn = (wave & 1) * 64;

  if (stid < 128) stok[stid] = tokens[(b0 + stid) * T_ + t];
  __syncthreads();

  f32x4 acc[4][4] = {};

  const int e0 = stid, e1 = 256 + stid;
  const int r0 = e0 >> 2, c0 = e0 & 3;
  const int r1 = e1 >> 2, c1 = e1 & 3;
  const int s0 = c0 ^ (r0 & 3) ^ ((r0 >> 2) & 3);
  const int s1 = c1 ^ (r1 & 3) ^ ((r1 >> 2) & 3);
  const int swr = q ^ (l & 3) ^ ((l >> 2) & 3);

  const bf16* B0 = Bt + (long)(n0 + r0) * K + s0 * 8;
  const bf16* B1 = Bt + (long)(n0 + r1) * K + s1 * 8;
  bf16* BsW0 = Bs + (wave * 64) * 8;
  bf16* BsW1 = Bs + (256 + wave * 64) * 8;

  const int ar = stid >> 1, hh = stid & 1;
  const int asw = (ar & 3) ^ ((ar >> 2) & 3);
  const float* er = emb + (long)stok[ar] * E_;

  for (int k0 = 0; k0 < K; k0 += 32) {
    __builtin_amdgcn_global_load_lds((const AS1 void*)(B0 + k0), (AS3 void*)BsW0, 16, 0, 0);
    __builtin_amdgcn_global_load_lds((const AS1 void*)(B1 + k0), (AS3 void*)BsW1, 16, 0, 0);
    bf16x8 v[2];
#pragma unroll
    for (int cch = 0; cch < 2; cch++) {
      int kb = k0 + hh * 16 + cch * 8;
#pragma unroll
      for (int j = 0; j < 8; j++) {
        int k = kb + j;
        v[cch][j] = (bf16)((k < E_) ? er[k] : 0.f);
      }
    }
    *(bf16x8*)(As + ar * 32 + ((2 * hh + 0) ^ asw) * 8) = v[0];
    *(bf16x8*)(As + ar * 32 + ((2 * hh + 1) ^ asw) * 8) = v[1];
    __syncthreads();
    bf16x8 af[4], bfm[4];
#pragma unroll
    for (int i = 0; i < 4; i++) {
      af[i]  = *(const bf16x8*)(As + (wm + i * 16 + l) * 32 + swr * 8);
      bfm[i] = *(const bf16x8*)(Bs + (wn + i * 16 + l) * 32 + swr * 8);
    }
#pragma unroll
    for (int i = 0; i < 4; i++)
#pragma unroll
      for (int j = 0; j < 4; j++)
        acc[i][j] = __builtin_amdgcn_mfma_f32_16x16x32_bf16(af[i], bfm[j], acc[i][j], 0, 0, 0);
    __syncthreads();
  }
  bf16* C = xwc + ((long)trow * B_ + b0) * H_;
#pragma unroll
  for (int i = 0; i < 4; i++)
#pragma unroll
    for (int j = 0; j < 4; j++)
#pragma unroll
      for (int r = 0; r < 4; r++)
        C[(long)(wm + i * 16 + q * 4 + r) * H_ + n0 + wn + j * 16 + l] =
            (bf16)acc[i][j][r];
}

// ---- Fused pipeline step, 512 thr/block (2 waves/SIMD -> 256 regs/lane) ----
// blocks 0..127: rnn(task t-1); blocks 128..255: gemm(task t), 2 subgroups x 4 tiles.
// gemm_wide=1: all 256 blocks gemm (2 tiles per sub-group), rnn off.
__global__ __launch_bounds__(512) void fused_step(
    const bf16* __restrict__ xwc_r, const unsigned char* __restrict__ U8,
    const float* __restrict__ bias, bf16* __restrict__ seq, int t0_r, int first,
    int rnn_on,
    const bf16* __restrict__ A, const bf16* __restrict__ Bt,
    bf16* __restrict__ xwc_g, int gemm_kind, int gemm_wide,
    const int* __restrict__ tokens, const float* __restrict__ emb, int t0_g) {
  __shared__ __align__(16) char smem[116480];
  const int tid = threadIdx.x;

  if (blockIdx.x < 128 && !gemm_wide) {
    if (!rnn_on) return;
    // ---------------- rnn path: 8 waves, wave = 16 rows x 64 cols ----------------
    char* hls8 = smem;                               // 2 x 16 x 520 B fp8 h
    bf16* xws = (bf16*)(smem + 16640);               // 4-buf xw staging
    bf16* hstg = (bf16*)(smem + 83200);              // 2-buf bf16 h staging
    const int wave = tid >> 6, lane = tid & 63;
    const int l = lane & 15, q = lane >> 4;
    const int b0 = blockIdx.x * ROWS_;

    // init h_{t0-1} into buffer 0: wave handles rows wave*2, wave*2+1
#pragma unroll
    for (int rr = 0; rr < 2; rr++) {
      int m = wave * 2 + rr;
      long pk = 0;
      if (!first) {
        const bf16* hsrc = seq + ((long)(t0_r - 1) * B_ + b0 + m) * H_;
        bf16x8 v = *(const bf16x8*)(hsrc + lane * 8);
        float f[8];
#pragma unroll
        for (int j = 0; j < 8; j++) f[j] = (float)v[j] * 16.f;
        pk = pack_fp8x8(f);
      }
      *(long*)(hls8 + m * 520 + lane * 8) = pk;
    }

    float bb[4];
#pragma unroll
    for (int nt = 0; nt < 4; nt++) bb[nt] = bias[wave * 64 + nt * 16 + l];

    auto prefetch = [&](int tl) {
      int buf = tl & 3;
#pragma unroll
      for (int rr = 0; rr < 2; rr++) {
        int row = wave * 2 + rr;
        __builtin_amdgcn_global_load_lds(
            (const AS1 void*)(xwc_r + ((long)tl * B_ + b0 + row) * H_ + lane * 8),
            (AS3 void*)(xws + (buf * ROWS_ + row) * 520), 16, 0, 0);
      }
    };

    prefetch(0);
    prefetch(1);
    __syncthreads();

    // wave's U: colblocks wave*4 .. wave*4+3 (8KB each)
    const unsigned char* Ub = U8 + (long)(wave * 4) * 8192 + lane * 16;

    for (int tl = 0; tl < TC_; tl++) {
      if (tl + 2 < TC_) prefetch(tl + 2);

      const char* hb8 = hls8 + ((tl & 1) * ROWS_ + l) * 520 + q * 8;
      f32x4 acc[4] = {};
      u64x2 bfr[3][4];
#pragma unroll
      for (int d = 0; d < 3; d++)
#pragma unroll
        for (int nt = 0; nt < 4; nt++)
          bfr[d][nt] = *(const u64x2*)(Ub + nt * 8192 + d * 1024);
#pragma unroll
      for (int kk2 = 0; kk2 < 8; kk2++) {
        const int cur = kk2 % 3;
        long a0 = *(const long*)(hb8 + kk2 * 64);
        long a1 = *(const long*)(hb8 + kk2 * 64 + 32);
#pragma unroll
        for (int nt = 0; nt < 4; nt++)
          acc[nt] = __builtin_amdgcn_mfma_f32_16x16x32_fp8_fp8(a0, (long)bfr[cur][nt].x,
                                                               acc[nt], 0, 0, 0);
#pragma unroll
        for (int nt = 0; nt < 4; nt++)
          acc[nt] = __builtin_amdgcn_mfma_f32_16x16x32_fp8_fp8(a1, (long)bfr[cur][nt].y,
                                                               acc[nt], 0, 0, 0);
        if (kk2 < 5) {
#pragma unroll
          for (int nt = 0; nt < 4; nt++)
            bfr[cur][nt] = *(const u64x2*)(Ub + nt * 8192 + (kk2 + 3) * 1024);
        }
      }
      const bf16* xr = xws + ((tl & 3) * ROWS_ + q * 4) * 520 + wave * 64 + l;
      float hv[4][4];
#pragma unroll
      for (int nt = 0; nt < 4; nt++)
#pragma unroll
        for (int r = 0; r < 4; r++)
          hv[nt][r] = fast_tanh((float)xr[r * 520 + nt * 16] + bb[nt] +
                                acc[nt][r] * 0.0009765625f);

#pragma unroll
      for (int nt = 0; nt < 4; nt++) {
        int n = wave * 64 + nt * 16 + l;
#pragma unroll
        for (int r = 0; r < 4; r++) {
          int m = q * 4 + r;
          hls8[(((tl + 1) & 1) * ROWS_ + m) * 520 + n] = (char)to_fp8(hv[nt][r] * 16.f);
          hstg[((tl & 1) * ROWS_ + m) * 520 + n] = (bf16)hv[nt][r];
        }
      }

      if (tl > 0) {
        bf16* sp = seq + ((long)(t0_r + tl - 1) * B_ + b0) * H_;
#pragma unroll
        for (int rr = 0; rr < 2; rr++) {
          int m = wave * 2 + rr;
          *(bf16x8*)(sp + (long)m * H_ + lane * 8) =
              *(const bf16x8*)(hstg + (((tl - 1) & 1) * ROWS_ + m) * 520 + lane * 8);
        }
      }

      __syncthreads();
    }
    {
      bf16* sp = seq + ((long)(t0_r + TC_ - 1) * B_ + b0) * H_;
#pragma unroll
      for (int rr = 0; rr < 2; rr++) {
        int m = wave * 2 + rr;
        *(bf16x8*)(sp + (long)m * H_ + lane * 8) =
            *(const bf16x8*)(hstg + (((TC_ - 1) & 1) * ROWS_ + m) * 520 + lane * 8);
      }
    }
    return;
  }

  // ---------------- gemm path: 2 subgroups of 256 thr ----------------
  if (!gemm_kind) return;
  const int sub = tid >> 8, stid = tid & 255;
  char* base = smem + sub * 17408;
  const int gb = gemm_wide ? blockIdx.x : blockIdx.x - 128;
  const int reps = gemm_wide ? 2 : 4;
  const int stride = gemm_wide ? 512 : 256;
  const int sb = gb * 2 + sub;
  for (int rep = 0; rep < reps; rep++) {
    int tau = sb + rep * stride;
    int x = tau & 255, y = tau >> 8;
    if (gemm_kind == 1)
      gemm_tile_embed(tokens, emb, Bt, xwc_g, t0_g, x, y, stid, base);
    else
      gemm_tile(A, Bt, xwc_g, x, y, stid, base);
  }
}

// out[b] = sigmoid(dot(seq[(T-1)*B + b, :], Wo) + bo)
__global__ __launch_bounds__(256) void head_kernel(
    const bf16* __restrict__ seq, const float* __restrict__ Wo,
    const float* __restrict__ bo, float* __restrict__ out) {
  int wave = threadIdx.x >> 6, lane = threadIdx.x & 63;
  int row = blockIdx.x * 4 + wave;
  const bf16* p = seq + ((long)(T_ - 1) * B_ + row) * H_ + lane * 8;
  bf16x8 v = *(const bf16x8*)p;
  float s = 0.f;
#pragma unroll
  for (int i = 0; i < 8; i++) s += (float)v[i] * Wo[lane * 8 + i];
#pragma unroll
  for (int off = 32; off; off >>= 1) s += __shfl_down(s, off, 64);
  if (lane == 0) {
    float x = s + bo[0];
    out[row] = 1.f / (1.f + exp2f(-x * 1.44269504088896f));
  }
}

extern "C" void kernel_launch(void* const* d_in, const int* in_sizes, int n_in,
                              void* d_out, int out_size, void* d_ws, size_t ws_size,
                              hipStream_t stream) {
  (void)in_sizes; (void)n_in; (void)out_size;
  const int*   tokens = (const int*)d_in[0];
  const float* emb = (const float*)d_in[1];
  const float* W1 = (const float*)d_in[2];
  const float* U1 = (const float*)d_in[3];
  const float* b1 = (const float*)d_in[4];
  const float* W2 = (const float*)d_in[5];
  const float* U2 = (const float*)d_in[6];
  const float* b2 = (const float*)d_in[7];
  const float* W3 = (const float*)d_in[8];
  const float* U3 = (const float*)d_in[9];
  const float* b3 = (const float*)d_in[10];
  const float* W4 = (const float*)d_in[11];
  const float* U4 = (const float*)d_in[12];
  const float* b4 = (const float*)d_in[13];
  const float* Wo = (const float*)d_in[14];
  const float* bo = (const float*)d_in[15];
  float* out = (float*)d_out;

  char* w = (char*)d_ws;
  const size_t SEQ_BYTES = (size_t)T_ * B_ * H_ * 2;   // 160 MB
  const size_t XWC_BYTES = (size_t)TC_ * B_ * H_ * 2;  // 32 MB
  const size_t WEIGHTS = 512 * 128 * 2 + 3 * 512 * 512 * 2 + 4 * 512 * 512;
  const bool dbl = ws_size >= SEQ_BYTES + 2 * XWC_BYTES + WEIGHTS;

  bf16* SEQ = (bf16*)w;
  bf16* XWC0 = (bf16*)(w + SEQ_BYTES);
  bf16* XWC1 = dbl ? (bf16*)(w + SEQ_BYTES + XWC_BYTES) : XWC0;
  char* wb = w + SEQ_BYTES + (dbl ? 2 : 1) * XWC_BYTES;
  bf16* W1t = (bf16*)wb;
  bf16* W2t = W1t + 512 * 128;
  bf16* W3t = W2t + 512 * 512;
  bf16* W4t = W3t + 512 * 512;
  unsigned char* U1p = (unsigned char*)(W4t + 512 * 512);
  unsigned char* U2p = U1p + 512 * 512;
  unsigned char* U3p = U2p + 512 * 512;
  unsigned char* U4p = U3p + 512 * 512;

  convert_weight<<<(512 * 128) / 256, 256, 0, stream>>>(W1, W1t, 100, 128, 512);
  convert_weight<<<(512 * 512) / 256, 256, 0, stream>>>(W2, W2t, 512, 512, 512);
  convert_weight<<<(512 * 512) / 256, 256, 0, stream>>>(W3, W3t, 512, 512, 512);
  convert_weight<<<(512 * 512) / 256, 256, 0, stream>>>(W4, W4t, 512, 512, 512);
  convert_u_fp8<<<128, 256, 0, stream>>>(U1, U1p);
  convert_u_fp8<<<128, 256, 0, stream>>>(U2, U2p);
  convert_u_fp8<<<128, 256, 0, stream>>>(U3, U3p);
  convert_u_fp8<<<128, 256, 0, stream>>>(U4, U4p);

  const bf16* Wt[4] = {W1t, W2t, W3t, W4t};
  const unsigned char* Up[4] = {U1p, U2p, U3p, U4p};
  const float* bs[4] = {b1, b2, b3, b4};
  bf16* XWCb[2] = {XWC0, XWC1};

  if (dbl) {
    // software pipeline: launch t = rnn(task t-1) || gemm(task t)
    for (int t = 0; t <= NTASK_; t++) {
      int rt = t - 1;
      int rl = rt < 0 ? 0 : rt / NC_, rc = rt < 0 ? 0 : rt % NC_;
      int gl = t >= NTASK_ ? 0 : t / NC_, gc = t >= NTASK_ ? 0 : t % NC_;
      int gkind = t >= NTASK_ ? 0 : (gl == 0 ? 1 : 2);
      int wide = (t == 0) ? 1 : 0;
      fused_step<<<256, 512, 0, stream>>>(
          XWCb[rt & 1], Up[rl], bs[rl], SEQ, rc * TC_, rc == 0 ? 1 : 0,
          rt >= 0 ? 1 : 0,
          SEQ + (size_t)gc * TC_ * B_ * H_, Wt[gl], XWCb[t & 1], gkind, wide,
          tokens, emb, gc * TC_);
    }
  } else {
    // serial fallback: one XWC buffer
    for (int t = 0; t < NTASK_; t++) {
      int l = t / NC_, c = t % NC_;
      int gkind = (l == 0 ? 1 : 2);
      fused_step<<<256, 512, 0, stream>>>(
          XWC0, Up[l], bs[l], SEQ, c * TC_, 0, 0,
          SEQ + (size_t)c * TC_ * B_ * H_, Wt[l], XWC0, gkind, 1,
          tokens, emb, c * TC_);
      fused_step<<<256, 512, 0, stream>>>(
          XWC0, Up[l], bs[l], SEQ, c * TC_, c == 0 ? 1 : 0, 1,
          SEQ, Wt[l], XWC0, 0, 0, tokens, emb, 0);
    }
  }

  head_kernel<<<B_ / 4, 256, 0, stream>>>(SEQ, Wo, bo, out);
}